// Round 4
// baseline (5650.187 us; speedup 1.0000x reference)
//
#include <hip/hip_runtime.h>
#include <hip/hip_fp16.h>

typedef unsigned int u32;
typedef _Float16 h2f __attribute__((ext_vector_type(2)));

#define BB 128
#define TT 512
#define DD 64
#define NBL 32
#define GIN 2080

// DPP: quad_perm xor1=0xB1 xor2=0x4E xor3=0x1B; half_mirror(xor7)=0x141;
// row_mirror(xor15)=0x140. All VALU-pipe.
template <int CTRL>
__device__ __forceinline__ float dpp_mov_f(float x) {
  return __builtin_bit_cast(
      float, __builtin_amdgcn_update_dpp(0, __builtin_bit_cast(int, x), CTRL,
                                         0xF, 0xF, true));
}
template <int CTRL>
__device__ __forceinline__ float dpp_add_f(float x) {
  return x + dpp_mov_f<CTRL>(x);
}
__device__ __forceinline__ float swz_add16(float x) {  // xor16 within 32
  return x + __builtin_bit_cast(float, __builtin_amdgcn_ds_swizzle(
                                           __builtin_bit_cast(int, x), 0x401F));
}
__device__ __forceinline__ float bpermf(int addr, float x) {
  return __builtin_bit_cast(
      float, __builtin_amdgcn_ds_bpermute(addr, __builtin_bit_cast(int, x)));
}
__device__ __forceinline__ float xorf(float a, u32 m) {
  return __builtin_bit_cast(float, __builtin_bit_cast(u32, a) ^ m);
}
__device__ __forceinline__ float uni_f(float v) {
  return __builtin_bit_cast(
      float, __builtin_amdgcn_readfirstlane(__builtin_bit_cast(int, v)));
}
__device__ __forceinline__ int uni_i(int v) {
  return __builtin_amdgcn_readfirstlane(v);
}

// sign of e_i * e_j in Cl(4,1): 1 if negative
__device__ inline int gp_negbit(int i, int j) {
  int sw = 0;
#pragma unroll
  for (int b = 0; b < 5; ++b)
    if ((j >> b) & 1) sw += __popc(i >> (b + 1));
  return (sw ^ ((i & j) >> 4)) & 1;  // METRIC[4] = -1
}

__device__ inline float fdot2f(u32 a, u32 b, float acc) {
#if __has_builtin(__builtin_amdgcn_fdot2)
  return __builtin_amdgcn_fdot2(__builtin_bit_cast(h2f, a),
                                __builtin_bit_cast(h2f, b), acc, false);
#else
  h2f av = __builtin_bit_cast(h2f, a), bv = __builtin_bit_cast(h2f, b);
  return acc + (float)av.x * (float)bv.x + (float)av.y * (float)bv.y;
#endif
}

__device__ inline u32 pkf16(float a, float b) {
  return __builtin_bit_cast(u32, __builtin_amdgcn_cvt_pkrtz(a, b));
}

// h16 flat layout: P(m, dd) = 16*dd + ((m + dd) & 15); pair m = blades
// (2m, 2m+1) of state row dd, packed f16x2. Gate lane l reads P in
// [16l, 16l+16) (pure stride-1 b128); state writes are <=2-way banked.
__global__ __launch_bounds__(1024, 4) void versor_fused(
    const int* __restrict__ x, const float* __restrict__ emb,
    const float* __restrict__ gate_w, const float* __restrict__ gate_b,
    const float* __restrict__ w1, const float* __restrict__ b1g,
    const float* __restrict__ ln_g, const float* __restrict__ ln_b,
    const float* __restrict__ w2, const float* __restrict__ b2,
    float* __restrict__ out) {
  __shared__ float rn[4][NBL];    // normalized emb rows (for rc only)
  __shared__ float inv_lds[4];    // 1/(||emb_row||+eps)
  __shared__ float rc[4][DD];     // r-part of gate, pre-dotted (normalized r)
  __shared__ __align__(16) u32 h16[2][1024];  // f16x2 state, rotated layout
  __shared__ __align__(16) float hs[2048];    // final h for head
  __shared__ float redA[16][2];
  __shared__ float redB[16][2];

  const int b = blockIdx.x;
  const int tid = threadIdx.x;
  const int w = tid >> 6;       // wave 0..15
  const int l = tid & 63;       // lane
  const int rl = l >> 4;        // row-in-wave 0..3
  const int d = (w << 2) + rl;  // this lane's state row
  const int c = l & 15;         // owner blade pair: owns {c, c+16}
  const int H = l >> 5;         // half (gate row-group)
  const int s = (l >> 4) & 1;   // row-within-halfgroup
  const int bp32 = ((l ^ 32) << 2);

  // ---- init: normalized embeddings + inverse norms ----
  if (tid < 4) {
    float v[NBL];
    float sum = 0.f;
    for (int i = 0; i < NBL; ++i) {
      v[i] = emb[tid * NBL + i];
      sum += v[i] * v[i];
    }
    float sc = 1.f / (sqrtf(sum) + 1e-8f);
    inv_lds[tid] = sc;
    for (int i = 0; i < NBL; ++i) rn[tid][i] = v[i] * sc;
  }
  // h16[0]: h0 = e0 per row: pair m=0 holds pack(1,0)
  for (int idx = tid; idx < 1024; idx += 1024) {
    int dd = idx >> 4;
    int m = ((idx & 15) - dd) & 15;
    h16[0][idx] = (m == 0) ? 0x00003C00u : 0u;
  }
  __syncthreads();

  // ---- rc[e][row] = sum_i gate_w[row][2048+i] * rn_normalized[e][i] ----
  if (tid < 256) {
    int e = tid >> 6, row = tid & 63;
    float sum = 0.f;
    for (int i = 0; i < NBL; ++i) sum += gate_w[row * GIN + 2048 + i] * rn[e][i];
    rc[e][row] = sum;
  }

  // ---- gate weights -> registers (f16x2): lane l covers h-row dd=l,
  // all 16 pairs, for 4 gate rows (its wave's rows, half-swapped) ----
  u32 gw[4][16];
#pragma unroll
  for (int rr = 0; rr < 4; ++rr) {
    const int grow = (w << 2) + (rr ^ (H << 1));
    const float* wp = gate_w + grow * GIN + l * 32;
#pragma unroll
    for (int j = 0; j < 16; ++j) {
      int m = (j - l) & 15;
      gw[rr][j] = pkf16(wp[2 * m], wp[2 * m + 1]);
    }
  }
  const float gb = gate_b[d];

  // ---- sign masks: sbl[m] for i=m (k=c); i=m+16 via parity rule ----
  u32 sbl[16];
#pragma unroll
  for (int m = 0; m < 16; ++m)
    sbl[m] = gp_negbit(m, m ^ c) ? 0x80000000u : 0u;
  const int pc = __popc(c) & 1;
  const u32 Me = ((u32)(pc ^ 1)) << 31;  // flip mask, even-popc m
  const u32 Mo = ((u32)pc) << 31;        // flip mask, odd-popc m
  __syncthreads();

  // per-lane copies (selected per step by uniform xi)
  float rcv0 = rc[0][d] + gb, rcv1 = rc[1][d] + gb;
  float rcv2 = rc[2][d] + gb, rcv3 = rc[3][d] + gb;
  float iv0 = inv_lds[0], iv1 = inv_lds[1], iv2 = inv_lds[2],
        iv3 = inv_lds[3];

  // register-resident state: u0 = h[d][c], u1 = h[d][c+16]
  float u0 = (c == 0) ? 1.f : 0.f, u1 = 0.f;

#define GPTERM(M, E0, E1)                                                  \
  do {                                                                     \
    float t0 = xorf(rnr[M], sbl[M]);                                       \
    float t1 = xorf(xorf(rnr[(M) + 16], sbl[M]),                           \
                    ((__builtin_popcount(M) & 1) ? Mo : Me));              \
    b0 = fmaf(t0, (E0), b0);                                               \
    b0 = fmaf(t1, (E1), b0);                                               \
    b1v = fmaf(t0, (E1), b1v);                                             \
    b1v = fmaf(-t1, (E0), b1v);                                            \
  } while (0)

  auto step = [&](int p, int xi, const float (&rnr)[NBL]) {
    const int pn = p ^ 1;

    // ---- gate: stride-1 b128 LDS reads + 64 f16 dot2 ----
    const u32* Hb = &h16[p][l << 4];
    u32 hvw[16];
    *(uint4*)&hvw[0] = *(const uint4*)(Hb + 0);
    *(uint4*)&hvw[4] = *(const uint4*)(Hb + 4);
    *(uint4*)&hvw[8] = *(const uint4*)(Hb + 8);
    *(uint4*)&hvw[12] = *(const uint4*)(Hb + 12);
    float a0 = 0.f, a1 = 0.f, a2 = 0.f, a3 = 0.f;
#pragma unroll
    for (int j = 0; j < 16; ++j) {
      a0 = fdot2f(gw[0][j], hvw[j], a0);
      a1 = fdot2f(gw[1][j], hvw[j], a1);
      a2 = fdot2f(gw[2][j], hvw[j], a2);
      a3 = fdot2f(gw[3][j], hvw[j], a3);
    }
    // reduce each accum to 32-half sums (4 DPP + swz16)
    a0 = dpp_add_f<0xB1>(a0); a0 = dpp_add_f<0x4E>(a0);
    a0 = dpp_add_f<0x141>(a0); a0 = dpp_add_f<0x140>(a0); a0 = swz_add16(a0);
    a1 = dpp_add_f<0xB1>(a1); a1 = dpp_add_f<0x4E>(a1);
    a1 = dpp_add_f<0x141>(a1); a1 = dpp_add_f<0x140>(a1); a1 = swz_add16(a1);
    a2 = dpp_add_f<0xB1>(a2); a2 = dpp_add_f<0x4E>(a2);
    a2 = dpp_add_f<0x141>(a2); a2 = dpp_add_f<0x140>(a2); a2 = swz_add16(a2);
    a3 = dpp_add_f<0xB1>(a3); a3 = dpp_add_f<0x4E>(a3);
    a3 = dpp_add_f<0x141>(a3); a3 = dpp_add_f<0x140>(a3); a3 = swz_add16(a3);
    // selA: this half's partial of MY row; selB: my partial of partner's row
    float selA = s ? a1 : a0;
    float selB = s ? a3 : a2;
    float zsum = selA + bpermf(bp32, selB);
    float rcsel = (xi == 0) ? rcv0 : (xi == 1) ? rcv1 : (xi == 2) ? rcv2 : rcv3;
    float invsel = (xi == 0) ? iv0 : (xi == 1) ? iv1 : (xi == 2) ? iv2 : iv3;
    float zg = zsum + rcsel;
    float g = 1.f / (1.f + exp2f(-1.44269504f * zg));

    // ---- geometric product, streamed butterfly (U[m] = xor_m of u0/u1) ----
    float b0 = 0.f, b1v = 0.f;
    {
      GPTERM(0, u0, u1);
      float e0 = dpp_mov_f<0xB1>(u0), e1 = dpp_mov_f<0xB1>(u1);
      GPTERM(1, e0, e1);
      e0 = dpp_mov_f<0x4E>(u0); e1 = dpp_mov_f<0x4E>(u1);
      GPTERM(2, e0, e1);
      e0 = dpp_mov_f<0x1B>(u0); e1 = dpp_mov_f<0x1B>(u1);
      GPTERM(3, e0, e1);
    }
    {
      float y70 = dpp_mov_f<0x141>(u0), y71 = dpp_mov_f<0x141>(u1);
      GPTERM(7, y70, y71);
      float e0 = dpp_mov_f<0xB1>(y70), e1 = dpp_mov_f<0xB1>(y71);
      GPTERM(6, e0, e1);
      e0 = dpp_mov_f<0x4E>(y70); e1 = dpp_mov_f<0x4E>(y71);
      GPTERM(5, e0, e1);
      e0 = dpp_mov_f<0x1B>(y70); e1 = dpp_mov_f<0x1B>(y71);
      GPTERM(4, e0, e1);
    }
    {
      float y150 = dpp_mov_f<0x140>(u0), y151 = dpp_mov_f<0x140>(u1);
      GPTERM(15, y150, y151);
      float e0 = dpp_mov_f<0xB1>(y150), e1 = dpp_mov_f<0xB1>(y151);
      GPTERM(14, e0, e1);
      e0 = dpp_mov_f<0x4E>(y150); e1 = dpp_mov_f<0x4E>(y151);
      GPTERM(13, e0, e1);
      e0 = dpp_mov_f<0x1B>(y150); e1 = dpp_mov_f<0x1B>(y151);
      GPTERM(12, e0, e1);
      float y80 = dpp_mov_f<0x141>(y150), y81 = dpp_mov_f<0x141>(y151);
      GPTERM(8, y80, y81);
      e0 = dpp_mov_f<0xB1>(y80); e1 = dpp_mov_f<0xB1>(y81);
      GPTERM(9, e0, e1);
      e0 = dpp_mov_f<0x4E>(y80); e1 = dpp_mov_f<0x4E>(y81);
      GPTERM(10, e0, e1);
      e0 = dpp_mov_f<0x1B>(y80); e1 = dpp_mov_f<0x1B>(y81);
      GPTERM(11, e0, e1);
    }

    // ---- gated update (r-norm folded post-dot) + mnorm over 16-lane row ----
    float gi = g * invsel;
    float om = 1.f - g;
    float nu0 = fmaf(gi, b0, om * u0);
    float nu1 = fmaf(gi, b1v, om * u1);
    float sq = nu0 * nu0 + nu1 * nu1;
    sq = dpp_add_f<0xB1>(sq);
    sq = dpp_add_f<0x4E>(sq);
    sq = dpp_add_f<0x141>(sq);
    sq = dpp_add_f<0x140>(sq);
    float sc = 1.f / (sqrtf(sq) + 1e-8f);
    u0 = nu0 * sc;
    u1 = nu1 * sc;

    // ---- pack f16x2 pairs (partner via DPP xor1), rotated layout ----
    float v0 = dpp_mov_f<0xB1>(u0);
    float v1 = dpp_mov_f<0xB1>(u1);
    if (!(l & 1)) {  // even c packs (c,c+1) and (c+16,c+17)
      int m0 = c >> 1, m1 = (c >> 1) + 8;
      h16[pn][(d << 4) + ((m0 + d) & 15)] = pkf16(u0, v0);
      h16[pn][(d << 4) + ((m1 + d) & 15)] = pkf16(u1, v1);
    }
    __syncthreads();
  };

  // ---- software-pipelined uniform loads of x / raw emb rows ----
  const int* xg = x + b * TT;
  int xiA = uni_i(xg[0]);
  int xiB = uni_i(xg[1]);
  float rnA[NBL], rnB[NBL];
#pragma unroll
  for (int i = 0; i < NBL; ++i) rnA[i] = uni_f(emb[xiA * NBL + i]);

  for (int t = 0; t < TT; t += 2) {
#pragma unroll
    for (int i = 0; i < NBL; ++i) rnB[i] = uni_f(emb[xiB * NBL + i]);
    int xiC = uni_i(xg[(t + 2 < TT) ? t + 2 : 0]);
    step(0, xiA, rnA);
#pragma unroll
    for (int i = 0; i < NBL; ++i) rnA[i] = uni_f(emb[xiC * NBL + i]);
    int xiD = uni_i(xg[(t + 3 < TT) ? t + 3 : 0]);
    step(1, xiB, rnB);
    xiA = xiC;
    xiB = xiD;
  }

  // ================= fused head =================
  hs[d * 32 + c] = u0;
  hs[d * 32 + c + 16] = u1;
  __syncthreads();

  const int hr = tid >> 3;  // output row 0..127
  const int seg = tid & 7;  // column segment (256 floats)
  float acc = 0.f;
  {
    const float4* w4 = (const float4*)(w1 + hr * 2048 + seg * 256);
    const float4* h4 = (const float4*)(hs + seg * 256);
#pragma unroll 8
    for (int k = 0; k < 64; ++k) {
      float4 a = w4[k], hv = h4[k];
      acc = fmaf(a.x, hv.x, acc);
      acc = fmaf(a.y, hv.y, acc);
      acc = fmaf(a.z, hv.z, acc);
      acc = fmaf(a.w, hv.w, acc);
    }
  }
  // reduce over 8 segments (aligned 8-lane groups)
  acc = dpp_add_f<0xB1>(acc);
  acc = dpp_add_f<0x4E>(acc);
  acc = dpp_add_f<0x141>(acc);
  float z = acc + b1g[hr];

  // LayerNorm stats over 128 rows (8 copies each -> /1024)
  float s1 = z, s2 = z * z;
  s1 = dpp_add_f<0xB1>(s1); s1 = dpp_add_f<0x4E>(s1);
  s1 = dpp_add_f<0x141>(s1); s1 = dpp_add_f<0x140>(s1);
  s1 = swz_add16(s1); s1 += bpermf(bp32, s1);
  s2 = dpp_add_f<0xB1>(s2); s2 = dpp_add_f<0x4E>(s2);
  s2 = dpp_add_f<0x141>(s2); s2 = dpp_add_f<0x140>(s2);
  s2 = swz_add16(s2); s2 += bpermf(bp32, s2);
  if (l == 0) { redA[w][0] = s1; redA[w][1] = s2; }
  __syncthreads();
  float tot1 = 0.f, tot2 = 0.f;
#pragma unroll
  for (int k = 0; k < 16; ++k) { tot1 += redA[k][0]; tot2 += redA[k][1]; }
  float mu = tot1 * (1.f / 1024.f);
  float var = tot2 * (1.f / 1024.f) - mu * mu;
  z = (z - mu) * rsqrtf(var + 1e-5f) * ln_g[hr] + ln_b[hr];
  z = fmaxf(z, 0.f);

  float c0 = (seg == 0) ? z * w2[hr] : 0.f;
  float c1 = (seg == 0) ? z * w2[128 + hr] : 0.f;
  c0 = dpp_add_f<0xB1>(c0); c0 = dpp_add_f<0x4E>(c0);
  c0 = dpp_add_f<0x141>(c0); c0 = dpp_add_f<0x140>(c0);
  c0 = swz_add16(c0); c0 += bpermf(bp32, c0);
  c1 = dpp_add_f<0xB1>(c1); c1 = dpp_add_f<0x4E>(c1);
  c1 = dpp_add_f<0x141>(c1); c1 = dpp_add_f<0x140>(c1);
  c1 = swz_add16(c1); c1 += bpermf(bp32, c1);
  if (l == 0) { redB[w][0] = c0; redB[w][1] = c1; }
  __syncthreads();
  if (tid == 0) {
    float p0 = 0.f, p1 = 0.f;
#pragma unroll
    for (int k = 0; k < 16; ++k) { p0 += redB[k][0]; p1 += redB[k][1]; }
    out[b * 2 + 0] = p0 + b2[0];
    out[b * 2 + 1] = p1 + b2[1];
  }
#undef GPTERM
}

extern "C" void kernel_launch(void* const* d_in, const int* in_sizes, int n_in,
                              void* d_out, int out_size, void* d_ws,
                              size_t ws_size, hipStream_t stream) {
  (void)in_sizes; (void)n_in; (void)out_size; (void)d_ws; (void)ws_size;
  const int* x = (const int*)d_in[0];
  const float* emb = (const float*)d_in[1];
  const float* gate_w = (const float*)d_in[2];
  const float* gate_b = (const float*)d_in[3];
  const float* w1 = (const float*)d_in[4];
  const float* b1 = (const float*)d_in[5];
  const float* ln_g = (const float*)d_in[6];
  const float* ln_b = (const float*)d_in[7];
  const float* w2 = (const float*)d_in[8];
  const float* b2 = (const float*)d_in[9];
  float* out = (float*)d_out;

  versor_fused<<<dim3(BB), dim3(1024), 0, stream>>>(
      x, emb, gate_w, gate_b, w1, b1, ln_g, ln_b, w2, b2, out);
}

// Round 5
// 925.899 us; speedup vs baseline: 6.1024x; 6.1024x over previous
//
#include <hip/hip_runtime.h>
#include <hip/hip_fp16.h>

typedef unsigned int u32;
typedef _Float16 h2f __attribute__((ext_vector_type(2)));

#define BB 128
#define TT 512
#define DD 64
#define NBL 32
#define GIN 2080

// DPP: quad_perm xor1=0xB1 xor2=0x4E xor3=0x1B; half_mirror(rev8=xor7)=0x141;
// row_mirror(rev16=xor15)=0x140. All VALU-pipe.
template <int CTRL>
__device__ __forceinline__ float dpp_mov_f(float x) {
  return __builtin_bit_cast(
      float, __builtin_amdgcn_update_dpp(0, __builtin_bit_cast(int, x), CTRL,
                                         0xF, 0xF, true));
}
template <int CTRL>
__device__ __forceinline__ float dpp_add_f(float x) {
  return x + dpp_mov_f<CTRL>(x);
}
__device__ __forceinline__ float swz_add16(float x) {  // xor16 within 32
  return x + __builtin_bit_cast(float, __builtin_amdgcn_ds_swizzle(
                                           __builtin_bit_cast(int, x), 0x401F));
}
__device__ __forceinline__ float bpermf(int addr, float x) {
  return __builtin_bit_cast(
      float, __builtin_amdgcn_ds_bpermute(addr, __builtin_bit_cast(int, x)));
}
__device__ __forceinline__ float xorf(float a, u32 m) {
  return __builtin_bit_cast(float, __builtin_bit_cast(u32, a) ^ m);
}
__device__ __forceinline__ float uni_f(float v) {
  return __builtin_bit_cast(
      float, __builtin_amdgcn_readfirstlane(__builtin_bit_cast(int, v)));
}
__device__ __forceinline__ int uni_i(int v) {
  return __builtin_amdgcn_readfirstlane(v);
}

// sign of e_i * e_j in Cl(4,1): 1 if negative
__device__ inline int gp_negbit(int i, int j) {
  int sw = 0;
#pragma unroll
  for (int b = 0; b < 5; ++b)
    if ((j >> b) & 1) sw += __popc(i >> (b + 1));
  return (sw ^ ((i & j) >> 4)) & 1;  // METRIC[4] = -1
}

__device__ inline float fdot2f(u32 a, u32 b, float acc) {
#if __has_builtin(__builtin_amdgcn_fdot2)
  return __builtin_amdgcn_fdot2(__builtin_bit_cast(h2f, a),
                                __builtin_bit_cast(h2f, b), acc, false);
#else
  h2f av = __builtin_bit_cast(h2f, a), bv = __builtin_bit_cast(h2f, b);
  return acc + (float)av.x * (float)bv.x + (float)av.y * (float)bv.y;
#endif
}

__device__ inline u32 pkf16(float a, float b) {
  return __builtin_bit_cast(u32, __builtin_amdgcn_cvt_pkrtz(a, b));
}

// Butterfly neighbor: (E0..E3) = (u0..u3) of lane l^Q, computed into e0..e3
// before this macro. Signs verified in R2/R3 (passing kernels).
#define GPQ(Q, E0, E1, E2, E3)                                   \
  do {                                                           \
    float t0 = xorf(RNR[(Q)], sb[(Q)]);                          \
    float t1 = xorf(RNR[(Q) + 8], sb[(Q) + 8]);                  \
    float t2 = xorf(RNR[(Q) + 16], sb[(Q) + 16]);                \
    float t3 = xorf(RNR[(Q) + 24], sb[(Q) + 24]);                \
    b0 = fmaf(t0, (E0), b0);                                     \
    b1 = fmaf(t0, (E1), b1);                                     \
    b2 = fmaf(t0, (E2), b2);                                     \
    b3 = fmaf(t0, (E3), b3);                                     \
    b0 = fmaf(t1, (E1), b0);                                     \
    b1 = fmaf(t1, (E0), b1);                                     \
    b2 = fmaf(t1, (E3), b2);                                     \
    b3 = fmaf(t1, (E2), b3);                                     \
    b0 = fmaf(t2, (E2), b0);                                     \
    b1 = fmaf(-t2, (E3), b1);                                    \
    b2 = fmaf(-t2, (E0), b2);                                    \
    b3 = fmaf(t2, (E1), b3);                                     \
    b0 = fmaf(t3, (E3), b0);                                     \
    b1 = fmaf(-t3, (E2), b1);                                    \
    b2 = fmaf(-t3, (E1), b2);                                    \
    b3 = fmaf(t3, (E0), b3);                                     \
  } while (0)

#define STEP(P, RNR, XI)                                                      \
  do {                                                                        \
    const int pn = (P) ^ 1;                                                   \
    /* gate: 8x b128 stride-1 LDS reads + 128 f16 dot2 (R2-verified map) */   \
    const u32* Hb = &h16t[(P)][s >> 1][(s & 1) << 5];                         \
    float a0 = 0.f, a1 = 0.f, a2 = 0.f, a3 = 0.f;                             \
    _Pragma("unroll") for (int jq = 0; jq < 8; ++jq) {                        \
      uint4 hv = *(const uint4*)(Hb + (jq << 2));                             \
      a0 = fdot2f(gw[0][4 * jq + 0], hv.x, a0);                               \
      a0 = fdot2f(gw[0][4 * jq + 1], hv.y, a0);                               \
      a0 = fdot2f(gw[0][4 * jq + 2], hv.z, a0);                               \
      a0 = fdot2f(gw[0][4 * jq + 3], hv.w, a0);                               \
      a1 = fdot2f(gw[1][4 * jq + 0], hv.x, a1);                               \
      a1 = fdot2f(gw[1][4 * jq + 1], hv.y, a1);                               \
      a1 = fdot2f(gw[1][4 * jq + 2], hv.z, a1);                               \
      a1 = fdot2f(gw[1][4 * jq + 3], hv.w, a1);                               \
      a2 = fdot2f(gw[2][4 * jq + 0], hv.x, a2);                               \
      a2 = fdot2f(gw[2][4 * jq + 1], hv.y, a2);                               \
      a2 = fdot2f(gw[2][4 * jq + 2], hv.z, a2);                               \
      a2 = fdot2f(gw[2][4 * jq + 3], hv.w, a2);                               \
      a3 = fdot2f(gw[3][4 * jq + 0], hv.x, a3);                               \
      a3 = fdot2f(gw[3][4 * jq + 1], hv.y, a3);                               \
      a3 = fdot2f(gw[3][4 * jq + 2], hv.z, a3);                               \
      a3 = fdot2f(gw[3][4 * jq + 3], hv.w, a3);                               \
    }                                                                         \
    a0 = dpp_add_f<0xB1>(a0); a0 = dpp_add_f<0x4E>(a0);                       \
    a0 = dpp_add_f<0x141>(a0); a0 = dpp_add_f<0x140>(a0); a0 = swz_add16(a0); \
    a1 = dpp_add_f<0xB1>(a1); a1 = dpp_add_f<0x4E>(a1);                       \
    a1 = dpp_add_f<0x141>(a1); a1 = dpp_add_f<0x140>(a1); a1 = swz_add16(a1); \
    a2 = dpp_add_f<0xB1>(a2); a2 = dpp_add_f<0x4E>(a2);                       \
    a2 = dpp_add_f<0x141>(a2); a2 = dpp_add_f<0x140>(a2); a2 = swz_add16(a2); \
    a3 = dpp_add_f<0xB1>(a3); a3 = dpp_add_f<0x4E>(a3);                       \
    a3 = dpp_add_f<0x141>(a3); a3 = dpp_add_f<0x140>(a3); a3 = swz_add16(a3); \
    const int jsel = rl & 3;                                                  \
    float zv = (jsel == 0) ? a0 : (jsel == 1) ? a1 : (jsel == 2) ? a2 : a3;   \
    float rcsel = ((XI) == 0)   ? rcv0                                        \
                  : ((XI) == 1) ? rcv1                                        \
                  : ((XI) == 2) ? rcv2                                        \
                                : rcv3;                                       \
    float invsel = ((XI) == 0)   ? iv0                                        \
                   : ((XI) == 1) ? iv1                                        \
                   : ((XI) == 2) ? iv2                                        \
                                 : iv3;                                       \
    float g = 1.f / (1.f + exp2f(-1.44269504f * (zv + rcsel)));               \
    /* GP: butterfly over 8-lane group, all DPP */                            \
    float b0 = 0.f, b1 = 0.f, b2 = 0.f, b3 = 0.f;                             \
    GPQ(0, u0, u1, u2, u3);                                                   \
    {                                                                         \
      float e0 = dpp_mov_f<0xB1>(u0), e1 = dpp_mov_f<0xB1>(u1);               \
      float e2 = dpp_mov_f<0xB1>(u2), e3 = dpp_mov_f<0xB1>(u3);               \
      GPQ(1, e0, e1, e2, e3);                                                 \
      e0 = dpp_mov_f<0x4E>(u0); e1 = dpp_mov_f<0x4E>(u1);                     \
      e2 = dpp_mov_f<0x4E>(u2); e3 = dpp_mov_f<0x4E>(u3);                     \
      GPQ(2, e0, e1, e2, e3);                                                 \
      e0 = dpp_mov_f<0x1B>(u0); e1 = dpp_mov_f<0x1B>(u1);                     \
      e2 = dpp_mov_f<0x1B>(u2); e3 = dpp_mov_f<0x1B>(u3);                     \
      GPQ(3, e0, e1, e2, e3);                                                 \
    }                                                                         \
    {                                                                         \
      float y0 = dpp_mov_f<0x141>(u0), y1 = dpp_mov_f<0x141>(u1);             \
      float y2 = dpp_mov_f<0x141>(u2), y3 = dpp_mov_f<0x141>(u3);             \
      GPQ(7, y0, y1, y2, y3);                                                 \
      float e0 = dpp_mov_f<0xB1>(y0), e1 = dpp_mov_f<0xB1>(y1);               \
      float e2 = dpp_mov_f<0xB1>(y2), e3 = dpp_mov_f<0xB1>(y3);               \
      GPQ(6, e0, e1, e2, e3);                                                 \
      e0 = dpp_mov_f<0x4E>(y0); e1 = dpp_mov_f<0x4E>(y1);                     \
      e2 = dpp_mov_f<0x4E>(y2); e3 = dpp_mov_f<0x4E>(y3);                     \
      GPQ(5, e0, e1, e2, e3);                                                 \
      e0 = dpp_mov_f<0x1B>(y0); e1 = dpp_mov_f<0x1B>(y1);                     \
      e2 = dpp_mov_f<0x1B>(y2); e3 = dpp_mov_f<0x1B>(y3);                     \
      GPQ(4, e0, e1, e2, e3);                                                 \
    }                                                                         \
    /* gated update (r-norm folded post-dot) + mnorm over 8-lane group */     \
    float gi = g * invsel;                                                    \
    float om = 1.f - g;                                                       \
    float nu0 = fmaf(gi, b0, om * u0);                                        \
    float nu1 = fmaf(gi, b1, om * u1);                                        \
    float nu2 = fmaf(gi, b2, om * u2);                                        \
    float nu3 = fmaf(gi, b3, om * u3);                                        \
    float sq = nu0 * nu0 + nu1 * nu1 + nu2 * nu2 + nu3 * nu3;                 \
    sq = dpp_add_f<0xB1>(sq);                                                 \
    sq = dpp_add_f<0x4E>(sq);                                                 \
    sq = dpp_add_f<0x141>(sq);                                                \
    float sc = 1.f / (sqrtf(sq) + 1e-8f);                                     \
    u0 = nu0 * sc; u1 = nu1 * sc; u2 = nu2 * sc; u3 = nu3 * sc;               \
    float v0 = dpp_mov_f<0xB1>(u0);                                           \
    float v1 = dpp_mov_f<0xB1>(u1);                                           \
    float v2 = dpp_mov_f<0xB1>(u2);                                           \
    float v3 = dpp_mov_f<0xB1>(u3);                                           \
    if (!(l & 1)) { /* even c packs (c,c+1) */                                \
      h16t[pn][(c) >> 1][d] = pkf16(u0, v0);                                  \
      h16t[pn][(c + 8) >> 1][d] = pkf16(u1, v1);                              \
      h16t[pn][(c + 16) >> 1][d] = pkf16(u2, v2);                             \
      h16t[pn][(c + 24) >> 1][d] = pkf16(u3, v3);                             \
    }                                                                         \
    __syncthreads();                                                          \
  } while (0)

__global__ __launch_bounds__(512)
__attribute__((amdgpu_waves_per_eu(2, 2))) void versor_fused(
    const int* __restrict__ x, const float* __restrict__ emb,
    const float* __restrict__ gate_w, const float* __restrict__ gate_b,
    const float* __restrict__ w1, const float* __restrict__ b1g,
    const float* __restrict__ ln_g, const float* __restrict__ ln_b,
    const float* __restrict__ w2, const float* __restrict__ b2,
    float* __restrict__ out) {
  __shared__ float rn[4][NBL];   // normalized emb rows (init/rc only)
  __shared__ float inv_lds[4];   // 1/(||emb_row||+eps)
  __shared__ float rc[4][DD];    // r-part of gate, pre-dotted
  __shared__ __align__(16) u32 h16t[2][16][68];  // f16x2 h transposed [pair][d]
  __shared__ __align__(16) float hs[2048];       // final h for head
  __shared__ float redA[8][2];
  __shared__ float redB[8][2];

  const int b = blockIdx.x;
  const int tid = threadIdx.x;
  const int w = tid >> 6;       // wave 0..7
  const int l = tid & 63;       // lane
  const int rl = l >> 3;        // 0..7
  const int d = (w << 3) + rl;  // this lane's state row
  const int c = l & 7;          // owner quad: owns blades {c,c+8,c+16,c+24}
  const int r2g = l >> 5;       // gate row-quad group within wave (0..1)
  const int s = l & 31;         // gate 32-dword column slice
  const int bp32 = ((l ^ 32) << 2);

  // ---- init: normalized embeddings + inverse norms ----
  if (tid < 4) {
    float v[NBL];
    float sum = 0.f;
    for (int i = 0; i < NBL; ++i) {
      v[i] = emb[tid * NBL + i];
      sum += v[i] * v[i];
    }
    float sc = 1.f / (sqrtf(sum) + 1e-8f);
    inv_lds[tid] = sc;
    for (int i = 0; i < NBL; ++i) rn[tid][i] = v[i] * sc;
  }
  for (int idx = tid; idx < 16 * 68; idx += 512) {
    int m = idx / 68, dd = idx - m * 68;
    h16t[0][m][dd] = (m == 0 && dd < 64) ? 0x00003C00u : 0u;  // pack(1.0h,0)
  }
  __syncthreads();

  // ---- rc[e][row] = sum_i gate_w[row][2048+i] * rn_normalized[e][i] ----
  if (tid < 256) {
    int e = tid >> 6, row = tid & 63;
    float sum = 0.f;
    for (int i = 0; i < NBL; ++i) sum += gate_w[row * GIN + 2048 + i] * rn[e][i];
    rc[e][row] = sum;
  }

  // ---- gate weights -> registers (f16x2), 4 rows x 32 dwords per lane ----
  u32 gw[4][32];
#pragma unroll
  for (int rr = 0; rr < 4; ++rr) {
    const int row = (w << 3) + (r2g << 2) + rr;
    const float* wp = gate_w + row * GIN;
#pragma unroll
    for (int m = 0; m < 32; ++m) {
      int Dd = 32 * s + m;  // h16 dword index = pair*64 + d
      int pair = Dd >> 6, dd = Dd & 63;
      int col = dd * 32 + 2 * pair;
      gw[rr][m] = pkf16(wp[col], wp[col + 1]);
    }
  }
  const float gb = gate_b[d];

  // ---- per-lane sign masks for k=c (i-indexed) ----
  u32 sb[NBL];
#pragma unroll
  for (int i = 0; i < NBL; ++i) sb[i] = gp_negbit(i, i ^ c) ? 0x80000000u : 0u;
  __syncthreads();

  // per-lane copies selected per step by uniform xi
  const float rcv0 = rc[0][d] + gb, rcv1 = rc[1][d] + gb;
  const float rcv2 = rc[2][d] + gb, rcv3 = rc[3][d] + gb;
  const float iv0 = inv_lds[0], iv1 = inv_lds[1];
  const float iv2 = inv_lds[2], iv3 = inv_lds[3];

  // register-resident state: u_j = h[d][c + 8j]
  float u0 = (c == 0) ? 1.f : 0.f, u1 = 0.f, u2 = 0.f, u3 = 0.f;

  // ---- software-pipelined scalar loads of x / raw emb rows ----
  const int* xg = x + b * TT;
  int xiA = uni_i(xg[0]);
  int xiB = uni_i(xg[1]);
  float rnA[NBL], rnB[NBL];
#pragma unroll
  for (int i = 0; i < NBL; ++i) rnA[i] = uni_f(emb[xiA * NBL + i]);

  for (int t = 0; t < TT; t += 2) {
#pragma unroll
    for (int i = 0; i < NBL; ++i) rnB[i] = uni_f(emb[xiB * NBL + i]);
    int xiC = uni_i(xg[(t + 2 < TT) ? t + 2 : 0]);
#define RNR rnA
    STEP(0, rnA, xiA);
#undef RNR
#pragma unroll
    for (int i = 0; i < NBL; ++i) rnA[i] = uni_f(emb[xiC * NBL + i]);
    int xiD = uni_i(xg[(t + 3 < TT) ? t + 3 : 0]);
#define RNR rnB
    STEP(1, rnB, xiB);
#undef RNR
    xiA = xiC;
    xiB = xiD;
  }

  // ================= fused head =================
  {
    float* ho = hs + d * 32 + c;
    ho[0] = u0;
    ho[8] = u1;
    ho[16] = u2;
    ho[24] = u3;
  }
  __syncthreads();

  const int hr = tid >> 2;  // output row 0..127
  const int seg = tid & 3;  // column segment (512 floats)
  float acc = 0.f;
  {
    const float4* w4 = (const float4*)(w1 + hr * 2048 + seg * 512);
    const float4* h4 = (const float4*)(hs + seg * 512);
#pragma unroll 8
    for (int k = 0; k < 128; ++k) {
      float4 a = w4[k], hv = h4[k];
      acc = fmaf(a.x, hv.x, acc);
      acc = fmaf(a.y, hv.y, acc);
      acc = fmaf(a.z, hv.z, acc);
      acc = fmaf(a.w, hv.w, acc);
    }
  }
  acc = dpp_add_f<0xB1>(acc);
  acc = dpp_add_f<0x4E>(acc);  // all 4 lanes of the quad hold full row dot
  float z = acc + b1g[hr];

  // LayerNorm stats over 128 rows (each row appears in 4 lanes -> /512)
  float s1 = z, s2 = z * z;
  s1 = dpp_add_f<0xB1>(s1); s1 = dpp_add_f<0x4E>(s1);
  s1 = dpp_add_f<0x141>(s1); s1 = dpp_add_f<0x140>(s1);
  s1 = swz_add16(s1); s1 += bpermf(bp32, s1);
  s2 = dpp_add_f<0xB1>(s2); s2 = dpp_add_f<0x4E>(s2);
  s2 = dpp_add_f<0x141>(s2); s2 = dpp_add_f<0x140>(s2);
  s2 = swz_add16(s2); s2 += bpermf(bp32, s2);
  if (l == 0) { redA[w][0] = s1; redA[w][1] = s2; }
  __syncthreads();
  float tot1 = 0.f, tot2 = 0.f;
#pragma unroll
  for (int k = 0; k < 8; ++k) { tot1 += redA[k][0]; tot2 += redA[k][1]; }
  float mu = tot1 * (1.f / 512.f);
  float var = tot2 * (1.f / 512.f) - mu * mu;
  z = (z - mu) * rsqrtf(var + 1e-5f) * ln_g[hr] + ln_b[hr];
  z = fmaxf(z, 0.f);

  float c0 = (seg == 0) ? z * w2[hr] : 0.f;
  float c1 = (seg == 0) ? z * w2[128 + hr] : 0.f;
  c0 = dpp_add_f<0xB1>(c0); c0 = dpp_add_f<0x4E>(c0);
  c0 = dpp_add_f<0x141>(c0); c0 = dpp_add_f<0x140>(c0);
  c0 = swz_add16(c0); c0 += bpermf(bp32, c0);
  c1 = dpp_add_f<0xB1>(c1); c1 = dpp_add_f<0x4E>(c1);
  c1 = dpp_add_f<0x141>(c1); c1 = dpp_add_f<0x140>(c1);
  c1 = swz_add16(c1); c1 += bpermf(bp32, c1);
  if (l == 0) { redB[w][0] = c0; redB[w][1] = c1; }
  __syncthreads();
  if (tid == 0) {
    float p0 = 0.f, p1 = 0.f;
#pragma unroll
    for (int k = 0; k < 8; ++k) { p0 += redB[k][0]; p1 += redB[k][1]; }
    out[b * 2 + 0] = p0 + b2[0];
    out[b * 2 + 1] = p1 + b2[1];
  }
}

extern "C" void kernel_launch(void* const* d_in, const int* in_sizes, int n_in,
                              void* d_out, int out_size, void* d_ws,
                              size_t ws_size, hipStream_t stream) {
  (void)in_sizes; (void)n_in; (void)out_size; (void)d_ws; (void)ws_size;
  const int* x = (const int*)d_in[0];
  const float* emb = (const float*)d_in[1];
  const float* gate_w = (const float*)d_in[2];
  const float* gate_b = (const float*)d_in[3];
  const float* w1 = (const float*)d_in[4];
  const float* b1 = (const float*)d_in[5];
  const float* ln_g = (const float*)d_in[6];
  const float* ln_b = (const float*)d_in[7];
  const float* w2 = (const float*)d_in[8];
  const float* b2 = (const float*)d_in[9];
  float* out = (float*)d_out;

  versor_fused<<<dim3(BB), dim3(512), 0, stream>>>(
      x, emb, gate_w, gate_b, w1, b1, ln_g, ln_b, w2, b2, out);
}